// Round 11
// baseline (201.265 us; speedup 1.0000x reference)
//
#include <hip/hip_runtime.h>
#include <hip/hip_bf16.h>

// Problem constants
#define LSEQ 512
#define BATCH 2
#define DIN 256
#define CDIM 128
#define ODIM 64

typedef __attribute__((ext_vector_type(8))) short bf16x8;
typedef __attribute__((ext_vector_type(4))) float f32x4;

static __device__ __forceinline__ unsigned short f32_to_bf16(float f) {
    unsigned int u = __float_as_uint(f);
    unsigned int r = (u + 0x7FFFu + ((u >> 16) & 1u)) >> 16;  // RNE
    return (unsigned short)r;
}
static __device__ __forceinline__ float bf16_to_f32(unsigned short h) {
    return __uint_as_float(((unsigned int)h) << 16);
}

// ---------------------------------------------------------------------------
// Phase 1 (4 rows per block, 256 blocks x 256 threads):
//   per row: LayerNorm -> a = xn@w1^T+b1, bvec = xn@w2^T+b2, u' = a@w4^T+b3.
//   Each thread reads its w1/w2 row ONCE and applies it to 4 rows (amortizes
//   the 256KB weight re-read 4x: 256MB -> 64MB of L2 traffic).
// ---------------------------------------------------------------------------
__global__ __launch_bounds__(256) void phase1_kernel(
    const float* __restrict__ x, const float* __restrict__ nw,
    const float* __restrict__ nb, const float* __restrict__ w1,
    const float* __restrict__ b1, const float* __restrict__ w2,
    const float* __restrict__ b2, const float* __restrict__ b3,
    const float* __restrict__ w4,
    float* __restrict__ af, float* __restrict__ up,
    unsigned short* __restrict__ bh, unsigned short* __restrict__ bl)
{
    const int g = blockIdx.x;        // row group: rows g*4 .. g*4+3
    const int t = threadIdx.x;
    const int wv = t >> 6;           // wave index = row within group
    const int lane = t & 63;

    __shared__ float xn[4][DIN];     // normalized rows
    __shared__ float ab[4][256];     // per row: a in [0..127], b in [128..255]

    // --- LayerNorm: wave wv owns row g*4+wv (wave-local reduce, no barrier) ---
    {
        const int row = g * 4 + wv;
        const int b = row >> 9;      // batch
        const int i = row & 511;     // sequence index; x is [L, B, D]
        const float4* xr4 = (const float4*)(x + ((size_t)i * BATCH + b) * DIN);
        float4 xv = xr4[lane];       // 64 lanes x 4 floats = 256
        float s  = xv.x + xv.y + xv.z + xv.w;
        float s2 = xv.x * xv.x + xv.y * xv.y + xv.z * xv.z + xv.w * xv.w;
        #pragma unroll
        for (int m = 1; m < 64; m <<= 1) {
            s  += __shfl_xor(s,  m, 64);
            s2 += __shfl_xor(s2, m, 64);
        }
        float mu = s * (1.0f / DIN);
        float var = s2 * (1.0f / DIN) - mu * mu;
        float rs = rsqrtf(var + 1e-5f);
        float4 nwv = ((const float4*)nw)[lane];
        float4 nbv = ((const float4*)nb)[lane];
        float4 o;
        o.x = (xv.x - mu) * rs * nwv.x + nbv.x;
        o.y = (xv.y - mu) * rs * nwv.y + nbv.y;
        o.z = (xv.z - mu) * rs * nwv.z + nbv.z;
        o.w = (xv.w - mu) * rs * nwv.w + nbv.w;
        ((float4*)xn[wv])[lane] = o;
    }
    __syncthreads();

    // --- a/b dot products: thread -> (half, c); one w-row applied to 4 rows ---
    const int half = t >> 7;         // 0 -> w1/a, 1 -> w2/b
    const int c = t & 127;
    const float4* wr4 = (const float4*)((half ? w2 : w1) + (size_t)c * DIN);
    const float bias = (half ? b2 : b1)[c];
    const float4* x0 = (const float4*)xn[0];
    const float4* x1 = (const float4*)xn[1];
    const float4* x2 = (const float4*)xn[2];
    const float4* x3 = (const float4*)xn[3];
    float acc0 = 0.f, acc1 = 0.f, acc2 = 0.f, acc3 = 0.f;
    #pragma unroll 8
    for (int d = 0; d < DIN / 4; ++d) {
        float4 wvv = wr4[d];
        float4 a0 = x0[d];           // broadcast within wave (uniform addr)
        float4 a1 = x1[d];
        float4 a2 = x2[d];
        float4 a3 = x3[d];
        acc0 = fmaf(a0.x, wvv.x, acc0); acc0 = fmaf(a0.y, wvv.y, acc0);
        acc0 = fmaf(a0.z, wvv.z, acc0); acc0 = fmaf(a0.w, wvv.w, acc0);
        acc1 = fmaf(a1.x, wvv.x, acc1); acc1 = fmaf(a1.y, wvv.y, acc1);
        acc1 = fmaf(a1.z, wvv.z, acc1); acc1 = fmaf(a1.w, wvv.w, acc1);
        acc2 = fmaf(a2.x, wvv.x, acc2); acc2 = fmaf(a2.y, wvv.y, acc2);
        acc2 = fmaf(a2.z, wvv.z, acc2); acc2 = fmaf(a2.w, wvv.w, acc2);
        acc3 = fmaf(a3.x, wvv.x, acc3); acc3 = fmaf(a3.y, wvv.y, acc3);
        acc3 = fmaf(a3.z, wvv.z, acc3); acc3 = fmaf(a3.w, wvv.w, acc3);
    }
    acc0 += bias; acc1 += bias; acc2 += bias; acc3 += bias;
    float accs[4] = {acc0, acc1, acc2, acc3};
    #pragma unroll
    for (int r = 0; r < 4; ++r) {
        ab[r][t] = accs[r];
        const int row = g * 4 + r;
        if (half == 0) {
            af[(size_t)row * CDIM + c] = accs[r];
        } else {
            unsigned short hs = f32_to_bf16(accs[r]);
            float rem = accs[r] - bf16_to_f32(hs);
            bh[(size_t)row * CDIM + c] = hs;
            bl[(size_t)row * CDIM + c] = f32_to_bf16(rem);
        }
    }
    __syncthreads();

    // --- u'_o = sum_c a_c * w4[o][c] + b3[o]: wave wv owns row g*4+wv ---
    {
        const int row = g * 4 + wv;
        const float4* a4  = (const float4*)ab[wv];        // a is [0..127]
        const float4* w44 = (const float4*)(w4 + (size_t)lane * CDIM);
        float u = 0.0f;
        #pragma unroll 8
        for (int d = 0; d < CDIM / 4; ++d) {
            float4 aa = a4[d];                            // uniform -> broadcast
            float4 ww = w44[d];
            u = fmaf(aa.x, ww.x, u);
            u = fmaf(aa.y, ww.y, u);
            u = fmaf(aa.z, ww.z, u);
            u = fmaf(aa.w, ww.w, u);
        }
        up[(size_t)row * ODIM + lane] = u + b3[lane];     // lane < 64 = ODIM
    }
}

// ---------------------------------------------------------------------------
// Phase 2: per (b,i): out[b,i,j,o] = sum_c bvec[b,j,c] * (a_ic*w3_oc - w4_oc)
//                                     + u'[b,i,o]
// GEMM with MFMA operands (A=S, B=bvec): D[m=o][n=j].  Each lane then holds
// 4 CONSECUTIVE o values for one j -> float4 nontemporal stores.
// S-fragments are wave-invariant (depend only on (ot,kc,lane)), so they are
// built COOPERATIVELY: wave wv computes ot=wv, shares via LDS (w3/w4 L2
// traffic and cvt math /4), then all waves load the full set to registers.
// Grid: 1024 blocks, 256 threads (4 waves, each owns 128 j's).
// ---------------------------------------------------------------------------
__global__ __launch_bounds__(256, 2) void phase2_kernel(
    const float* __restrict__ w3, const float* __restrict__ w4,
    const float* __restrict__ af, const float* __restrict__ up,
    const unsigned short* __restrict__ bh, const unsigned short* __restrict__ bl,
    float* __restrict__ out)
{
    const int bid = blockIdx.x;
    const int b = bid >> 9;
    const int i = bid & 511;
    const int t = threadIdx.x;
    const int lane = t & 63;
    const int wave = t >> 6;
    const int l15 = lane & 15;
    const int lg  = lane >> 4;

    const float* a_row = af + (size_t)(b * LSEQ + i) * CDIM;

    // [h/l][ot][kc][lane] split-S fragments, 32 KiB
    __shared__ bf16x8 sfrag[2][4][4][64];

    // --- Cooperative S-build: S_i[c][o] = a_ic*w3[o][c] - w4[o][c] ---
    // Fragment lane-mapping (A and B sides identical): outer(o)=lane&15,
    // k(c)=(lane>>4)*8+reg; any within-k HW permutation cancels (shared with
    // the b-side fragments).  Value at (ot,kc,lane) is wave-independent.
    {
        const int ot = wave;                       // wave wv owns ot = wv
        const int o  = ot * 16 + l15;
        const float4* w3r = (const float4*)(w3 + (size_t)o * CDIM);
        const float4* w4r = (const float4*)(w4 + (size_t)o * CDIM);
        #pragma unroll
        for (int kc = 0; kc < 4; ++kc) {
            const int c0 = kc * 32 + lg * 8;       // element offset
            const int f4 = c0 >> 2;                // float4 index
            float av[8], w3v[8], w4v[8];
            float4 tmp;
            tmp = *(const float4*)(a_row + c0);
            av[0]=tmp.x; av[1]=tmp.y; av[2]=tmp.z; av[3]=tmp.w;
            tmp = *(const float4*)(a_row + c0 + 4);
            av[4]=tmp.x; av[5]=tmp.y; av[6]=tmp.z; av[7]=tmp.w;
            tmp = w3r[f4];     w3v[0]=tmp.x; w3v[1]=tmp.y; w3v[2]=tmp.z; w3v[3]=tmp.w;
            tmp = w3r[f4 + 1]; w3v[4]=tmp.x; w3v[5]=tmp.y; w3v[6]=tmp.z; w3v[7]=tmp.w;
            tmp = w4r[f4];     w4v[0]=tmp.x; w4v[1]=tmp.y; w4v[2]=tmp.z; w4v[3]=tmp.w;
            tmp = w4r[f4 + 1]; w4v[4]=tmp.x; w4v[5]=tmp.y; w4v[6]=tmp.z; w4v[7]=tmp.w;
            bf16x8 vh, vl;
            #pragma unroll
            for (int r = 0; r < 8; ++r) {
                float sv = fmaf(av[r], w3v[r], -w4v[r]);
                unsigned short hs = f32_to_bf16(sv);
                float rem = sv - bf16_to_f32(hs);
                vh[r] = (short)hs;
                vl[r] = (short)f32_to_bf16(rem);
            }
            sfrag[0][ot][kc][lane] = vh;
            sfrag[1][ot][kc][lane] = vl;
        }
    }
    __syncthreads();

    // All waves load the full fragment set (ds_read_b128, 16B/lane contiguous)
    bf16x8 Sh[4][4], Sl[4][4];
    #pragma unroll
    for (int ot = 0; ot < 4; ++ot)
        #pragma unroll
        for (int kc = 0; kc < 4; ++kc) {
            Sh[ot][kc] = sfrag[0][ot][kc][lane];
            Sl[ot][kc] = sfrag[1][ot][kc][lane];
        }

    // u' preload: 4 consecutive o values per lane, matching the D layout
    // (o = ot*16 + lg*4 + r).
    f32x4 uo[4];
    {
        const float* urow = up + (size_t)(b * LSEQ + i) * ODIM;
        #pragma unroll
        for (int ot = 0; ot < 4; ++ot)
            uo[ot] = *(const f32x4*)(urow + ot * 16 + lg * 4);
    }

    const unsigned short* bhb = bh + (size_t)b * LSEQ * CDIM;
    const unsigned short* blb = bl + (size_t)b * LSEQ * CDIM;
    float* outrow = out + (size_t)(b * LSEQ + i) * LSEQ * ODIM;

    const int jw = wave * 128;
    for (int jt = 0; jt < 4; ++jt) {
        const int j0 = jw + jt * 32;
        f32x4 acc[2][4];
        #pragma unroll
        for (int jj = 0; jj < 2; ++jj)
            #pragma unroll
            for (int ot = 0; ot < 4; ++ot)
                acc[jj][ot] = (f32x4){0.f, 0.f, 0.f, 0.f};

        #pragma unroll
        for (int kc = 0; kc < 4; ++kc) {
            const int c0 = kc * 32 + lg * 8;
            // b-side fragment: outer(j) = lane&15, k(c) = (lane>>4)*8 + reg
            bf16x8 Ah0 = *(const bf16x8*)(bhb + (size_t)(j0 +      l15) * CDIM + c0);
            bf16x8 Ah1 = *(const bf16x8*)(bhb + (size_t)(j0 + 16 + l15) * CDIM + c0);
            bf16x8 Al0 = *(const bf16x8*)(blb + (size_t)(j0 +      l15) * CDIM + c0);
            bf16x8 Al1 = *(const bf16x8*)(blb + (size_t)(j0 + 16 + l15) * CDIM + c0);
            #pragma unroll
            for (int ot = 0; ot < 4; ++ot) {
                // A = S (rows = o), B = bvec (cols = j)  ->  D[m=o][n=j]
                acc[0][ot] = __builtin_amdgcn_mfma_f32_16x16x32_bf16(Sh[ot][kc], Ah0, acc[0][ot], 0, 0, 0);
                acc[1][ot] = __builtin_amdgcn_mfma_f32_16x16x32_bf16(Sh[ot][kc], Ah1, acc[1][ot], 0, 0, 0);
                acc[0][ot] = __builtin_amdgcn_mfma_f32_16x16x32_bf16(Sl[ot][kc], Ah0, acc[0][ot], 0, 0, 0);
                acc[1][ot] = __builtin_amdgcn_mfma_f32_16x16x32_bf16(Sl[ot][kc], Ah1, acc[1][ot], 0, 0, 0);
                acc[0][ot] = __builtin_amdgcn_mfma_f32_16x16x32_bf16(Sh[ot][kc], Al0, acc[0][ot], 0, 0, 0);
                acc[1][ot] = __builtin_amdgcn_mfma_f32_16x16x32_bf16(Sh[ot][kc], Al1, acc[1][ot], 0, 0, 0);
            }
        }

        // Epilogue: D mapping col(n=j)=lane&15, row(m=o)=(lane>>4)*4 + r.
        // Lane holds out[j, ot*16+lg*4 .. +3] -> one nt dwordx4 per (jj,ot).
        // Non-temporal: out is write-only, never re-read; preserve L2 for
        // bh/bl/w3/w4 which every block re-reads.
        #pragma unroll
        for (int jj = 0; jj < 2; ++jj) {
            const int j = j0 + jj * 16 + l15;
            float* jrow = outrow + (size_t)j * ODIM;
            #pragma unroll
            for (int ot = 0; ot < 4; ++ot) {
                f32x4 v = acc[jj][ot] + uo[ot];
                __builtin_nontemporal_store(v, (f32x4*)(jrow + ot * 16 + lg * 4));
            }
        }
    }
}

// ---------------------------------------------------------------------------
extern "C" void kernel_launch(void* const* d_in, const int* in_sizes, int n_in,
                              void* d_out, int out_size, void* d_ws, size_t ws_size,
                              hipStream_t stream) {
    const float* x   = (const float*)d_in[0];
    const float* nw  = (const float*)d_in[1];
    const float* nb  = (const float*)d_in[2];
    const float* w1  = (const float*)d_in[3];
    const float* b1  = (const float*)d_in[4];
    const float* w2  = (const float*)d_in[5];
    const float* b2  = (const float*)d_in[6];
    const float* w3  = (const float*)d_in[7];
    const float* b3  = (const float*)d_in[8];
    const float* w4  = (const float*)d_in[9];
    float* out = (float*)d_out;

    // Workspace layout (floats): af[131072] | up[65536] | bh[65536] | bl[65536]
    // Total 1.25 MiB; fully rewritten by phase1 each call (0xAA-poison safe).
    float* ws = (float*)d_ws;
    float* af = ws;                               // [B][L][C] f32
    float* up = ws + 131072;                      // [B][L][O] f32
    unsigned short* bh = (unsigned short*)(ws + 196608); // [B][L][C] bf16 hi
    unsigned short* bl = (unsigned short*)(ws + 262144); // [B][L][C] bf16 lo

    phase1_kernel<<<BATCH * LSEQ / 4, 256, 0, stream>>>(x, nw, nb, w1, b1, w2,
                                                        b2, b3, w4, af, up, bh, bl);
    phase2_kernel<<<BATCH * LSEQ, 256, 0, stream>>>(w3, w4, af, up, bh, bl, out);
}

// Round 12
// 194.977 us; speedup vs baseline: 1.0322x; 1.0322x over previous
//
#include <hip/hip_runtime.h>
#include <hip/hip_bf16.h>

// Problem constants
#define LSEQ 512
#define BATCH 2
#define DIN 256
#define CDIM 128
#define ODIM 64

typedef __attribute__((ext_vector_type(8))) short bf16x8;
typedef __attribute__((ext_vector_type(4))) float f32x4;

static __device__ __forceinline__ unsigned short f32_to_bf16(float f) {
    unsigned int u = __float_as_uint(f);
    unsigned int r = (u + 0x7FFFu + ((u >> 16) & 1u)) >> 16;  // RNE
    return (unsigned short)r;
}
static __device__ __forceinline__ float bf16_to_f32(unsigned short h) {
    return __uint_as_float(((unsigned int)h) << 16);
}

// ---------------------------------------------------------------------------
// Phase 1 (4 rows per block, 256 blocks x 256 threads):
//   per row: LayerNorm -> a = xn@w1^T+b1, bvec = xn@w2^T+b2, u' = a@w4^T+b3.
//   Each thread reads its w1/w2 row ONCE and applies it to 4 rows (amortizes
//   the 256KB weight re-read 4x: 256MB -> 64MB of L2 traffic).
// ---------------------------------------------------------------------------
__global__ __launch_bounds__(256) void phase1_kernel(
    const float* __restrict__ x, const float* __restrict__ nw,
    const float* __restrict__ nb, const float* __restrict__ w1,
    const float* __restrict__ b1, const float* __restrict__ w2,
    const float* __restrict__ b2, const float* __restrict__ b3,
    const float* __restrict__ w4,
    float* __restrict__ af, float* __restrict__ up,
    unsigned short* __restrict__ bh, unsigned short* __restrict__ bl)
{
    const int g = blockIdx.x;        // row group: rows g*4 .. g*4+3
    const int t = threadIdx.x;
    const int wv = t >> 6;           // wave index = row within group
    const int lane = t & 63;

    __shared__ float xn[4][DIN];     // normalized rows
    __shared__ float ab[4][256];     // per row: a in [0..127], b in [128..255]

    // --- LayerNorm: wave wv owns row g*4+wv (wave-local reduce, no barrier) ---
    {
        const int row = g * 4 + wv;
        const int b = row >> 9;      // batch
        const int i = row & 511;     // sequence index; x is [L, B, D]
        const float4* xr4 = (const float4*)(x + ((size_t)i * BATCH + b) * DIN);
        float4 xv = xr4[lane];       // 64 lanes x 4 floats = 256
        float s  = xv.x + xv.y + xv.z + xv.w;
        float s2 = xv.x * xv.x + xv.y * xv.y + xv.z * xv.z + xv.w * xv.w;
        #pragma unroll
        for (int m = 1; m < 64; m <<= 1) {
            s  += __shfl_xor(s,  m, 64);
            s2 += __shfl_xor(s2, m, 64);
        }
        float mu = s * (1.0f / DIN);
        float var = s2 * (1.0f / DIN) - mu * mu;
        float rs = rsqrtf(var + 1e-5f);
        float4 nwv = ((const float4*)nw)[lane];
        float4 nbv = ((const float4*)nb)[lane];
        float4 o;
        o.x = (xv.x - mu) * rs * nwv.x + nbv.x;
        o.y = (xv.y - mu) * rs * nwv.y + nbv.y;
        o.z = (xv.z - mu) * rs * nwv.z + nbv.z;
        o.w = (xv.w - mu) * rs * nwv.w + nbv.w;
        ((float4*)xn[wv])[lane] = o;
    }
    __syncthreads();

    // --- a/b dot products: thread -> (half, c); one w-row applied to 4 rows ---
    const int half = t >> 7;         // 0 -> w1/a, 1 -> w2/b
    const int c = t & 127;
    const float4* wr4 = (const float4*)((half ? w2 : w1) + (size_t)c * DIN);
    const float bias = (half ? b2 : b1)[c];
    const float4* x0 = (const float4*)xn[0];
    const float4* x1 = (const float4*)xn[1];
    const float4* x2 = (const float4*)xn[2];
    const float4* x3 = (const float4*)xn[3];
    float acc0 = 0.f, acc1 = 0.f, acc2 = 0.f, acc3 = 0.f;
    #pragma unroll 8
    for (int d = 0; d < DIN / 4; ++d) {
        float4 wvv = wr4[d];
        float4 a0 = x0[d];           // broadcast within wave (uniform addr)
        float4 a1 = x1[d];
        float4 a2 = x2[d];
        float4 a3 = x3[d];
        acc0 = fmaf(a0.x, wvv.x, acc0); acc0 = fmaf(a0.y, wvv.y, acc0);
        acc0 = fmaf(a0.z, wvv.z, acc0); acc0 = fmaf(a0.w, wvv.w, acc0);
        acc1 = fmaf(a1.x, wvv.x, acc1); acc1 = fmaf(a1.y, wvv.y, acc1);
        acc1 = fmaf(a1.z, wvv.z, acc1); acc1 = fmaf(a1.w, wvv.w, acc1);
        acc2 = fmaf(a2.x, wvv.x, acc2); acc2 = fmaf(a2.y, wvv.y, acc2);
        acc2 = fmaf(a2.z, wvv.z, acc2); acc2 = fmaf(a2.w, wvv.w, acc2);
        acc3 = fmaf(a3.x, wvv.x, acc3); acc3 = fmaf(a3.y, wvv.y, acc3);
        acc3 = fmaf(a3.z, wvv.z, acc3); acc3 = fmaf(a3.w, wvv.w, acc3);
    }
    acc0 += bias; acc1 += bias; acc2 += bias; acc3 += bias;
    float accs[4] = {acc0, acc1, acc2, acc3};
    #pragma unroll
    for (int r = 0; r < 4; ++r) {
        ab[r][t] = accs[r];
        const int row = g * 4 + r;
        if (half == 0) {
            af[(size_t)row * CDIM + c] = accs[r];
        } else {
            unsigned short hs = f32_to_bf16(accs[r]);
            float rem = accs[r] - bf16_to_f32(hs);
            bh[(size_t)row * CDIM + c] = hs;
            bl[(size_t)row * CDIM + c] = f32_to_bf16(rem);
        }
    }
    __syncthreads();

    // --- u'_o = sum_c a_c * w4[o][c] + b3[o]: wave wv owns row g*4+wv ---
    {
        const int row = g * 4 + wv;
        const float4* a4  = (const float4*)ab[wv];        // a is [0..127]
        const float4* w44 = (const float4*)(w4 + (size_t)lane * CDIM);
        float u = 0.0f;
        #pragma unroll 8
        for (int d = 0; d < CDIM / 4; ++d) {
            float4 aa = a4[d];                            // uniform -> broadcast
            float4 ww = w44[d];
            u = fmaf(aa.x, ww.x, u);
            u = fmaf(aa.y, ww.y, u);
            u = fmaf(aa.z, ww.z, u);
            u = fmaf(aa.w, ww.w, u);
        }
        up[(size_t)row * ODIM + lane] = u + b3[lane];     // lane < 64 = ODIM
    }
}

// ---------------------------------------------------------------------------
// Phase 2: per (b,i): out[b,i,j,o] = sum_c bvec[b,j,c] * (a_ic*w3_oc - w4_oc)
//                                     + u'[b,i,o]
// GEMM with MFMA operands (A=S, B=bvec): D[m=o][n=j].  Each lane then holds
// 4 CONSECUTIVE o values for one j -> float4 stores.
// R11 change: PLAIN stores (was nontemporal).  Theory: nt bypasses L2, so the
// 16-segment-of-64B per-instruction store pattern can't write-combine into
// full lines -> HBM write inefficiency.  Plain stores let L2 assemble lines
// (the fills that hit 6.3 TB/s go through L2).  L3 (256 MiB) holds the whole
// working set, so L2 pollution from the output stream is cheap.
// Grid: 1024 blocks, 256 threads (4 waves, each owns 128 j's).
// ---------------------------------------------------------------------------
__global__ __launch_bounds__(256, 2) void phase2_kernel(
    const float* __restrict__ w3, const float* __restrict__ w4,
    const float* __restrict__ af, const float* __restrict__ up,
    const unsigned short* __restrict__ bh, const unsigned short* __restrict__ bl,
    float* __restrict__ out)
{
    const int bid = blockIdx.x;
    const int b = bid >> 9;
    const int i = bid & 511;
    const int t = threadIdx.x;
    const int lane = t & 63;
    const int wave = t >> 6;
    const int l15 = lane & 15;
    const int lg  = lane >> 4;

    const float* a_row = af + (size_t)(b * LSEQ + i) * CDIM;

    // [h/l][ot][kc][lane] split-S fragments, 32 KiB
    __shared__ bf16x8 sfrag[2][4][4][64];

    // --- Cooperative S-build: S_i[c][o] = a_ic*w3[o][c] - w4[o][c] ---
    // Fragment lane-mapping (A and B sides identical): outer(o)=lane&15,
    // k(c)=(lane>>4)*8+reg; any within-k HW permutation cancels (shared with
    // the b-side fragments).  Value at (ot,kc,lane) is wave-independent.
    {
        const int ot = wave;                       // wave wv owns ot = wv
        const int o  = ot * 16 + l15;
        const float4* w3r = (const float4*)(w3 + (size_t)o * CDIM);
        const float4* w4r = (const float4*)(w4 + (size_t)o * CDIM);
        #pragma unroll
        for (int kc = 0; kc < 4; ++kc) {
            const int c0 = kc * 32 + lg * 8;       // element offset
            const int f4 = c0 >> 2;                // float4 index
            float av[8], w3v[8], w4v[8];
            float4 tmp;
            tmp = *(const float4*)(a_row + c0);
            av[0]=tmp.x; av[1]=tmp.y; av[2]=tmp.z; av[3]=tmp.w;
            tmp = *(const float4*)(a_row + c0 + 4);
            av[4]=tmp.x; av[5]=tmp.y; av[6]=tmp.z; av[7]=tmp.w;
            tmp = w3r[f4];     w3v[0]=tmp.x; w3v[1]=tmp.y; w3v[2]=tmp.z; w3v[3]=tmp.w;
            tmp = w3r[f4 + 1]; w3v[4]=tmp.x; w3v[5]=tmp.y; w3v[6]=tmp.z; w3v[7]=tmp.w;
            tmp = w4r[f4];     w4v[0]=tmp.x; w4v[1]=tmp.y; w4v[2]=tmp.z; w4v[3]=tmp.w;
            tmp = w4r[f4 + 1]; w4v[4]=tmp.x; w4v[5]=tmp.y; w4v[6]=tmp.z; w4v[7]=tmp.w;
            bf16x8 vh, vl;
            #pragma unroll
            for (int r = 0; r < 8; ++r) {
                float sv = fmaf(av[r], w3v[r], -w4v[r]);
                unsigned short hs = f32_to_bf16(sv);
                float rem = sv - bf16_to_f32(hs);
                vh[r] = (short)hs;
                vl[r] = (short)f32_to_bf16(rem);
            }
            sfrag[0][ot][kc][lane] = vh;
            sfrag[1][ot][kc][lane] = vl;
        }
    }
    __syncthreads();

    // All waves load the full fragment set (ds_read_b128, 16B/lane contiguous)
    bf16x8 Sh[4][4], Sl[4][4];
    #pragma unroll
    for (int ot = 0; ot < 4; ++ot)
        #pragma unroll
        for (int kc = 0; kc < 4; ++kc) {
            Sh[ot][kc] = sfrag[0][ot][kc][lane];
            Sl[ot][kc] = sfrag[1][ot][kc][lane];
        }

    // u' preload: 4 consecutive o values per lane, matching the D layout
    // (o = ot*16 + lg*4 + r).
    f32x4 uo[4];
    {
        const float* urow = up + (size_t)(b * LSEQ + i) * ODIM;
        #pragma unroll
        for (int ot = 0; ot < 4; ++ot)
            uo[ot] = *(const f32x4*)(urow + ot * 16 + lg * 4);
    }

    const unsigned short* bhb = bh + (size_t)b * LSEQ * CDIM;
    const unsigned short* blb = bl + (size_t)b * LSEQ * CDIM;
    float* outrow = out + (size_t)(b * LSEQ + i) * LSEQ * ODIM;

    const int jw = wave * 128;
    for (int jt = 0; jt < 4; ++jt) {
        const int j0 = jw + jt * 32;
        f32x4 acc[2][4];
        #pragma unroll
        for (int jj = 0; jj < 2; ++jj)
            #pragma unroll
            for (int ot = 0; ot < 4; ++ot)
                acc[jj][ot] = (f32x4){0.f, 0.f, 0.f, 0.f};

        #pragma unroll
        for (int kc = 0; kc < 4; ++kc) {
            const int c0 = kc * 32 + lg * 8;
            // b-side fragment: outer(j) = lane&15, k(c) = (lane>>4)*8 + reg
            bf16x8 Ah0 = *(const bf16x8*)(bhb + (size_t)(j0 +      l15) * CDIM + c0);
            bf16x8 Ah1 = *(const bf16x8*)(bhb + (size_t)(j0 + 16 + l15) * CDIM + c0);
            bf16x8 Al0 = *(const bf16x8*)(blb + (size_t)(j0 +      l15) * CDIM + c0);
            bf16x8 Al1 = *(const bf16x8*)(blb + (size_t)(j0 + 16 + l15) * CDIM + c0);
            #pragma unroll
            for (int ot = 0; ot < 4; ++ot) {
                // A = S (rows = o), B = bvec (cols = j)  ->  D[m=o][n=j]
                acc[0][ot] = __builtin_amdgcn_mfma_f32_16x16x32_bf16(Sh[ot][kc], Ah0, acc[0][ot], 0, 0, 0);
                acc[1][ot] = __builtin_amdgcn_mfma_f32_16x16x32_bf16(Sh[ot][kc], Ah1, acc[1][ot], 0, 0, 0);
                acc[0][ot] = __builtin_amdgcn_mfma_f32_16x16x32_bf16(Sl[ot][kc], Ah0, acc[0][ot], 0, 0, 0);
                acc[1][ot] = __builtin_amdgcn_mfma_f32_16x16x32_bf16(Sl[ot][kc], Ah1, acc[1][ot], 0, 0, 0);
                acc[0][ot] = __builtin_amdgcn_mfma_f32_16x16x32_bf16(Sh[ot][kc], Al0, acc[0][ot], 0, 0, 0);
                acc[1][ot] = __builtin_amdgcn_mfma_f32_16x16x32_bf16(Sh[ot][kc], Al1, acc[1][ot], 0, 0, 0);
            }
        }

        // Epilogue: D mapping col(n=j)=lane&15, row(m=o)=(lane>>4)*4 + r.
        // Lane holds out[j, ot*16+lg*4 .. +3] -> one dwordx4 per (jj,ot).
        // PLAIN stores (R11): let L2 write-combine the 64B segments into
        // full lines before HBM.
        #pragma unroll
        for (int jj = 0; jj < 2; ++jj) {
            const int j = j0 + jj * 16 + l15;
            float* jrow = outrow + (size_t)j * ODIM;
            #pragma unroll
            for (int ot = 0; ot < 4; ++ot) {
                f32x4 v = acc[jj][ot] + uo[ot];
                *(f32x4*)(jrow + ot * 16 + lg * 4) = v;
            }
        }
    }
}

// ---------------------------------------------------------------------------
extern "C" void kernel_launch(void* const* d_in, const int* in_sizes, int n_in,
                              void* d_out, int out_size, void* d_ws, size_t ws_size,
                              hipStream_t stream) {
    const float* x   = (const float*)d_in[0];
    const float* nw  = (const float*)d_in[1];
    const float* nb  = (const float*)d_in[2];
    const float* w1  = (const float*)d_in[3];
    const float* b1  = (const float*)d_in[4];
    const float* w2  = (const float*)d_in[5];
    const float* b2  = (const float*)d_in[6];
    const float* w3  = (const float*)d_in[7];
    const float* b3  = (const float*)d_in[8];
    const float* w4  = (const float*)d_in[9];
    float* out = (float*)d_out;

    // Workspace layout (floats): af[131072] | up[65536] | bh[65536] | bl[65536]
    // Total 1.25 MiB; fully rewritten by phase1 each call (0xAA-poison safe).
    float* ws = (float*)d_ws;
    float* af = ws;                               // [B][L][C] f32
    float* up = ws + 131072;                      // [B][L][O] f32
    unsigned short* bh = (unsigned short*)(ws + 196608); // [B][L][C] bf16 hi
    unsigned short* bl = (unsigned short*)(ws + 262144); // [B][L][C] bf16 lo

    phase1_kernel<<<BATCH * LSEQ / 4, 256, 0, stream>>>(x, nw, nb, w1, b1, w2,
                                                        b2, b3, w4, af, up, bh, bl);
    phase2_kernel<<<BATCH * LSEQ, 256, 0, stream>>>(w3, w4, af, up, bh, bl, out);
}